// Round 6
// baseline (148.772 us; speedup 1.0000x reference)
//
#include <hip/hip_runtime.h>

typedef _Float16 half8 __attribute__((ext_vector_type(8)));
typedef float floatx16 __attribute__((ext_vector_type(16)));

constexpr int C = 32, H = 512, W = 512, HW = H * W;
constexpr int TBW = 32;             // output px per block (one 32-wide column)
constexpr int TBH = 4;              // output rows per block (1 per wave)
constexpr int RR  = TBH + 2;        // 6 staged input rows (h0-1 .. h0+4)
constexpr int PX  = TBW + 8;        // 40 staged px per row (w0-4 .. w0+35)
constexpr int PXW = 20;             // words/px: 16 x-fp16 + 2 depth(e-,e+) + 2 pad
constexpr int ROWW = PX * PXW + 4;  // 804 words; %32==4 skews row base banks

__device__ __forceinline__ unsigned pack2h(float lo, float hi) {
    unsigned a = (unsigned)__builtin_bit_cast(unsigned short, (_Float16)lo);
    unsigned b = (unsigned)__builtin_bit_cast(unsigned short, (_Float16)hi);
    return a | (b << 16);
}

// ---- weights -> per-lane fp16 A-frags for mfma_f32_32x32x16_f16.
// A[m][k], m = lane&31 (out-ch); k-half kh covers input ch 16kh + 8*(lane>>5) + j.
__global__ __launch_bounds__(256) void pack_w(const float* __restrict__ weight,
                                              uint4* __restrict__ wp) {
    int j = blockIdx.x * 256 + threadIdx.x;
    if (j >= 1152) return;                       // 9 taps * 2 khalves * 64 lanes
    int lane = j & 63, kh = (j >> 6) & 1, tap = j >> 7;
    int m = lane & 31, hh = lane >> 5;
    const float* wb = weight + (size_t)(m * 32 + kh * 16 + hh * 8) * 9 + tap;
    uint4 v;
    v.x = pack2h(wb[0 * 9], wb[1 * 9]);
    v.y = pack2h(wb[2 * 9], wb[3 * 9]);
    v.z = pack2h(wb[4 * 9], wb[5 * 9]);
    v.w = pack2h(wb[6 * 9], wb[7 * 9]);
    wp[j] = v;
}

// ---- fused conv, 32x32x16 MFMA. Wave = 1 output row x 32 px x 32 ch.
// This round: register-depth restructure. A-frags live in VGPRs the whole
// kernel; stage loads batched under one vmcnt (clamped addresses, select-zero
// after the wait); compute fully unrolled with 1-tap read-ahead rotation.
__global__ __launch_bounds__(256, 3) void depthconv_fused(
    const float* __restrict__ x, const float* __restrict__ depth,
    const uint4* __restrict__ wp, const float* __restrict__ bias,
    float* __restrict__ out)
{
    __shared__ __attribute__((aligned(16))) unsigned xsl[RR * ROWW];  // 19.3 KB

    // XCD column-stripes: xcd = bid&7 owns a 64-px stripe (2.6 MB x -> fits L2).
    const int bid  = blockIdx.x;
    const int xcd  = bid & 7, sub = (bid >> 3) & 1;
    const int hseg = (bid >> 4) & 127, b = bid >> 11;
    const int w0 = (xcd * 2 + sub) * TBW, h0 = hseg * TBH;
    const int tid = threadIdx.x;
    const int lane = tid & 63, wid = tid >> 6;
    const int pcl = lane & 31, hh = lane >> 5;   // px-in-tile, k-subgroup

    // ---- A-frags first: 72 VGPRs, held live across the whole kernel
    half8 afA[9], afB[9];
    #pragma unroll
    for (int t = 0; t < 9; ++t) {
        afA[t] = __builtin_bit_cast(half8, wp[t * 128 + lane]);
        afB[t] = __builtin_bit_cast(half8, wp[t * 128 + 64 + lane]);
    }

    // ---- stage x: 960 units (f4 fast, cp, r). All loads issued back-to-back
    // with clamped (always-valid) addresses; zero-select happens post-wait.
    float4 va[4], vb[4];
    bool okk[4], hask[4];
    int f4k[4], cpk[4], rk[4];
    #pragma unroll
    for (int k = 0; k < 4; ++k) {
        int u = tid + k * 256;
        bool has = (k < 3) || (tid < 192);       // wave-uniform tail guard
        int f4 = u % 10, t = u / 10, cp = t & 15, r = t >> 4;
        f4k[k] = f4; cpk[k] = cp; rk[k] = r; hask[k] = has;
        int h = h0 - 1 + r, wst = w0 - 4 + 4 * f4;
        okk[k] = ((unsigned)h < (unsigned)H) && ((unsigned)wst < (unsigned)W);
        int hc = h < 0 ? 0 : (h > H - 1 ? H - 1 : h);
        int wc = wst < 0 ? 0 : (wst > W - 4 ? W - 4 : wst);
        const float* xb = x + ((size_t)(b * C + 2 * cp)) * HW + (size_t)hc * W + wc;
        va[k] = *(const float4*)xb;              // unconditional: batches deep
        vb[k] = *(const float4*)(xb + HW);
    }

    // depth load, also unconditional via clamp
    float dval = 0.f; bool dok = false; int dpx = 0, dr = 0;
    {
        int u = tid;                             // 240 units; tail lanes harmless
        int px = u % PX, r = u / PX;
        dpx = px; dr = r;
        int h = h0 - 1 + r, ww = w0 - 4 + px;
        dok = (u < RR * PX) && ((unsigned)h < (unsigned)H) && ((unsigned)ww < (unsigned)W);
        int hc = h < 0 ? 0 : (h > H - 1 ? H - 1 : h);
        int wc = ww < 0 ? 0 : (ww > W - 1 ? W - 1 : ww);
        dval = depth[(size_t)b * HW + (size_t)hc * W + wc];
    }

    // ---- pack + LDS writes (single wait covers all loads above)
    #pragma unroll
    for (int k = 0; k < 4; ++k) {
        if (k == 3 && tid >= 192) continue;      // wave-uniform
        float4 A = va[k], B = vb[k];
        if (!okk[k]) { A = make_float4(0,0,0,0); B = make_float4(0,0,0,0); }
        int word = 4 * ((cpk[k] >> 2) ^ ((f4k[k] >> 1) & 3)) + (cpk[k] & 3);
        unsigned* dst = &xsl[rk[k] * ROWW + (4 * f4k[k]) * PXW + word];
        dst[0 * PXW] = pack2h(A.x, B.x);
        dst[1 * PXW] = pack2h(A.y, B.y);
        dst[2 * PXW] = pack2h(A.z, B.z);
        dst[3 * PXW] = pack2h(A.w, B.w);
    }
    if (tid < RR * PX) {
        float2 e = dok ? make_float2(__expf(-8.3f * dval), __expf(8.3f * dval))
                       : make_float2(0.f, 0.f);
        *(float2*)&xsl[dr * ROWW + dpx * PXW + 16] = e;
    }

    // acc init from bias: C/D row(ch) = (i&3) + 8*(i>>2) + 4*hh
    floatx16 accA, accB;
    #pragma unroll
    for (int g = 0; g < 4; ++g) {
        float4 bv = *(const float4*)(bias + g * 8 + 4 * hh);
        accA[4 * g + 0] = bv.x; accA[4 * g + 1] = bv.y;
        accA[4 * g + 2] = bv.z; accA[4 * g + 3] = bv.w;
        accB[4 * g + 0] = 0.f;  accB[4 * g + 1] = 0.f;
        accB[4 * g + 2] = 0.f;  accB[4 * g + 3] = 0.f;
    }

    __syncthreads();

    // ---- sims for all 9 taps up front (batched b64 reads, independent VALU)
    const float2 dc = *(const float2*)&xsl[(wid + 1) * ROWW + (pcl + 4) * PXW + 16];
    float2 dnv[9];
    #pragma unroll
    for (int t = 0; t < 9; ++t) {
        int ki = t / 3, kj = t % 3, p = pcl + 3 + kj;
        dnv[t] = *(const float2*)&xsl[(wid + ki) * ROWW + p * PXW + 16];
    }
    _Float16 sh[9];
    #pragma unroll
    for (int t = 0; t < 9; ++t)
        sh[t] = (_Float16)fminf(dnv[t].y * dc.x, dnv[t].x * dc.y);  // exp(-8.3|dc-dn|)

    // ---- x reads with 1-tap rotation: reads for tap t+1 issue before tap t's MFMAs
    auto rdx = [&](int t, int g) -> uint4 {
        int ki = t / 3, kj = t % 3, p = pcl + 3 + kj, key = (p >> 3) & 3;
        const unsigned* rec = &xsl[(wid + ki) * ROWW + p * PXW];
        return *(const uint4*)(rec + 4 * (g ^ key));
    };
    uint4 c0 = rdx(0, hh), c1 = rdx(0, 2 + hh);
    #pragma unroll
    for (int t = 0; t < 9; ++t) {
        uint4 n0, n1;
        if (t < 8) { n0 = rdx(t + 1, hh); n1 = rdx(t + 1, 2 + hh); }
        _Float16 hs = sh[t];
        half8 sv = { hs, hs, hs, hs, hs, hs, hs, hs };
        accA = __builtin_amdgcn_mfma_f32_32x32x16_f16(
                   afA[t], __builtin_bit_cast(half8, c0) * sv, accA, 0, 0, 0);
        accB = __builtin_amdgcn_mfma_f32_32x32x16_f16(
                   afB[t], __builtin_bit_cast(half8, c1) * sv, accB, 0, 0, 0);
        c0 = n0; c1 = n1;
    }

    // ---- epilogue: 16 coalesced b32 stores (32 px contiguous per 32-lane group)
    float* op = out + (size_t)b * C * HW + (size_t)(h0 + wid) * W + w0 + pcl;
    #pragma unroll
    for (int i = 0; i < 16; ++i) {
        int ch = (i & 3) + 8 * (i >> 2) + 4 * hh;
        op[(size_t)ch * HW] = accA[i] + accB[i];
    }
}

extern "C" void kernel_launch(void* const* d_in, const int* in_sizes, int n_in,
                              void* d_out, int out_size, void* d_ws, size_t ws_size,
                              hipStream_t stream) {
    const float* x      = (const float*)d_in[0];
    const float* depth  = (const float*)d_in[1];
    const float* weight = (const float*)d_in[2];
    const float* bias   = (const float*)d_in[3];
    float* out          = (float*)d_out;

    uint4* wpk = (uint4*)d_ws;                   // 18.4 KB, only ws user

    hipLaunchKernelGGL(pack_w, dim3(5), dim3(256), 0, stream, weight, wpk);
    // grid: 8 xcd * 2 sub * 128 hseg * 2 b = 4096
    hipLaunchKernelGGL(depthconv_fused, dim3(4096), dim3(256), 0, stream,
                       x, depth, wpk, bias, out);
}

// Round 7
// 142.955 us; speedup vs baseline: 1.0407x; 1.0407x over previous
//
#include <hip/hip_runtime.h>

typedef _Float16 half8 __attribute__((ext_vector_type(8)));
typedef float floatx16 __attribute__((ext_vector_type(16)));

constexpr int C = 32, H = 512, W = 512, HW = H * W;
constexpr int TBW = 32;             // output px per block (one 32-wide column)
constexpr int TBH = 4;              // output rows per block (1 per wave)
constexpr int RR  = TBH + 2;        // 6 staged input rows (h0-1 .. h0+4)
constexpr int PX  = TBW + 8;        // 40 staged px per row (w0-4 .. w0+35)
constexpr int PXW = 20;             // words/px: 16 x-fp16 + 2 depth(e-,e+) + 2 pad
constexpr int ROWW = PX * PXW + 4;  // 804 words; %32==4 skews row base banks

__device__ __forceinline__ unsigned pack2h(float lo, float hi) {
    unsigned a = (unsigned)__builtin_bit_cast(unsigned short, (_Float16)lo);
    unsigned b = (unsigned)__builtin_bit_cast(unsigned short, (_Float16)hi);
    return a | (b << 16);
}

// ---- weights -> per-lane fp16 A-frags for mfma_f32_32x32x16_f16.
// A[m][k], m = lane&31 (out-ch); k-half kh covers input ch 16kh + 8*(lane>>5) + j.
__global__ __launch_bounds__(256) void pack_w(const float* __restrict__ weight,
                                              uint4* __restrict__ wp) {
    int j = blockIdx.x * 256 + threadIdx.x;
    if (j >= 1152) return;                       // 9 taps * 2 khalves * 64 lanes
    int lane = j & 63, kh = (j >> 6) & 1, tap = j >> 7;
    int m = lane & 31, hh = lane >> 5;
    const float* wb = weight + (size_t)(m * 32 + kh * 16 + hh * 8) * 9 + tap;
    uint4 v;
    v.x = pack2h(wb[0 * 9], wb[1 * 9]);
    v.y = pack2h(wb[2 * 9], wb[3 * 9]);
    v.z = pack2h(wb[4 * 9], wb[5 * 9]);
    v.w = pack2h(wb[6 * 9], wb[7 * 9]);
    wp[j] = v;
}

// ---- fused conv, 32x32x16 MFMA. Wave = 1 output row x 32 px x 32 ch.
// R7 change vs R5: ONLY the bid->space mapping. Each XCD (dispatch round-robin
// on bid&7) owns a contiguous 64-row horizontal band; within the band blocks
// run w-fast, so the 16 column-blocks of one 4-row strip are co-resident on
// one XCD -> full DRAM-page read/write locality through that XCD's L2.
__global__ __launch_bounds__(256, 4) void depthconv_fused(
    const float* __restrict__ x, const float* __restrict__ depth,
    const uint4* __restrict__ wp, const float* __restrict__ bias,
    float* __restrict__ out)
{
    __shared__ __attribute__((aligned(16))) unsigned xsl[RR * ROWW];  // 19.3 KB

    const int bid  = blockIdx.x;
    const int band = bid & 7;                    // XCD id (round-robin dispatch)
    const int m    = bid >> 3;                   // 0..511 within band
    const int wseg = m & 15;                     // w-fast: 16 blocks = one strip
    const int hsub = (m >> 4) & 15;
    const int b    = (m >> 8) & 1;
    const int w0 = wseg * TBW;
    const int h0 = (band * 16 + hsub) * TBH;     // band = 64 contiguous rows
    const int tid = threadIdx.x;
    const int lane = tid & 63, wid = tid >> 6;
    const int pcl = lane & 31, hh = lane >> 5;   // px-in-tile, k-subgroup

    // ---- stage x: unit = (f4 fast, cp, r): 2 coalesced float4 loads
    // (ch 2cp,2cp+1 x 4px) -> 4 packed b32 LDS writes. 960 units.
    #pragma unroll
    for (int k = 0; k < 4; ++k) {
        int u = tid + k * 256;
        if (u < 960) {
            int f4 = u % 10, t = u / 10, cp = t & 15, r = t >> 4;
            int h = h0 - 1 + r, wst = w0 - 4 + 4 * f4;
            bool valid = ((unsigned)h < (unsigned)H) && ((unsigned)wst < (unsigned)W);
            float4 va = {0.f, 0.f, 0.f, 0.f}, vb = {0.f, 0.f, 0.f, 0.f};
            if (valid) {
                const float* xb = x + ((size_t)(b * C + 2 * cp)) * HW + (size_t)h * W + wst;
                va = *(const float4*)xb;
                vb = *(const float4*)(xb + HW);
            }
            // chunk-XOR: stored chunk = (cp>>2) ^ ((p>>3)&3); (p>>3) == f4>>1 for all 4 px
            int word = 4 * ((cp >> 2) ^ ((f4 >> 1) & 3)) + (cp & 3);
            unsigned* dst = &xsl[r * ROWW + (4 * f4) * PXW + word];
            dst[0 * PXW] = pack2h(va.x, vb.x);
            dst[1 * PXW] = pack2h(va.y, vb.y);
            dst[2 * PXW] = pack2h(va.z, vb.z);
            dst[3 * PXW] = pack2h(va.w, vb.w);
        }
    }

    // ---- stage depth: 240 units (one pass), words 16..17 of each record
    if (tid < RR * PX) {
        int px = tid % PX, r = tid / PX;
        int h = h0 - 1 + r, ww = w0 - 4 + px;
        bool valid = ((unsigned)h < (unsigned)H) && ((unsigned)ww < (unsigned)W);
        float d = valid ? depth[(size_t)b * HW + (size_t)h * W + ww] : 0.f;
        float2 e = valid ? make_float2(__expf(-8.3f * d), __expf(8.3f * d))
                         : make_float2(0.f, 0.f);
        *(float2*)&xsl[r * ROWW + px * PXW + 16] = e;
    }

    // acc init from bias while stage lands: C/D row(ch) = (i&3) + 8*(i>>2) + 4*hh
    floatx16 accA, accB;                         // kh=0 / kh=1 chains (ILP)
    #pragma unroll
    for (int g = 0; g < 4; ++g) {
        float4 bv = *(const float4*)(bias + g * 8 + 4 * hh);
        accA[4 * g + 0] = bv.x; accA[4 * g + 1] = bv.y;
        accA[4 * g + 2] = bv.z; accA[4 * g + 3] = bv.w;
        accB[4 * g + 0] = 0.f;  accB[4 * g + 1] = 0.f;
        accB[4 * g + 2] = 0.f;  accB[4 * g + 3] = 0.f;
    }

    __syncthreads();

    // center sim pair for this wave's output row (slot wid+1), px pcl
    const float2 dc = *(const float2*)&xsl[(wid + 1) * ROWW + (pcl + 4) * PXW + 16];

    #pragma unroll
    for (int ki = 0; ki < 3; ++ki) {
        const unsigned* srow = &xsl[(wid + ki) * ROWW];
        const uint4* wpt = wp + (size_t)(ki * 3) * 128;
        #pragma clang loop unroll(disable)
        for (int kj = 0; kj < 3; ++kj) {
            int p = pcl + 3 + kj;                // neighbor px (w0+pcl) + kj - 1
            int key = (p >> 3) & 3;
            const unsigned* rec = srow + p * PXW;
            uint4 x0 = *(const uint4*)(rec + 4 * (hh ^ key));        // ch 8hh..+7
            uint4 x1 = *(const uint4*)(rec + 4 * ((2 + hh) ^ key));  // ch 16+8hh..+7
            float2 dn = *(const float2*)(rec + 16);
            float s = fminf(dn.y * dc.x, dn.x * dc.y);   // exp(-8.3|dc-dn|)
            _Float16 hs = (_Float16)s;
            half8 sv = { hs, hs, hs, hs, hs, hs, hs, hs };
            half8 a0 = __builtin_bit_cast(half8, wpt[kj * 128 + lane]);
            half8 a1 = __builtin_bit_cast(half8, wpt[kj * 128 + 64 + lane]);
            accA = __builtin_amdgcn_mfma_f32_32x32x16_f16(
                       a0, __builtin_bit_cast(half8, x0) * sv, accA, 0, 0, 0);
            accB = __builtin_amdgcn_mfma_f32_32x32x16_f16(
                       a1, __builtin_bit_cast(half8, x1) * sv, accB, 0, 0, 0);
        }
    }

    // ---- epilogue: 16 coalesced b32 stores (32 px per 32-lane group per ch)
    float* op = out + (size_t)b * C * HW + (size_t)(h0 + wid) * W + w0 + pcl;
    #pragma unroll
    for (int i = 0; i < 16; ++i) {
        int ch = (i & 3) + 8 * (i >> 2) + 4 * hh;
        op[(size_t)ch * HW] = accA[i] + accB[i];
    }
}

extern "C" void kernel_launch(void* const* d_in, const int* in_sizes, int n_in,
                              void* d_out, int out_size, void* d_ws, size_t ws_size,
                              hipStream_t stream) {
    const float* x      = (const float*)d_in[0];
    const float* depth  = (const float*)d_in[1];
    const float* weight = (const float*)d_in[2];
    const float* bias   = (const float*)d_in[3];
    float* out          = (float*)d_out;

    uint4* wpk = (uint4*)d_ws;                   // 18.4 KB, only ws user

    hipLaunchKernelGGL(pack_w, dim3(5), dim3(256), 0, stream, weight, wpk);
    // grid: 8 bands * (16 wseg * 16 hsub * 2 b) = 4096
    hipLaunchKernelGGL(depthconv_fused, dim3(4096), dim3(256), 0, stream,
                       x, depth, wpk, bias, out);
}